// Round 2
// baseline (3066.779 us; speedup 1.0000x reference)
//
#include <hip/hip_runtime.h>

#define TST   1024
#define OWNW  8            // own tile: 8 wide
#define OWNH  32           // own tile: 32 tall
#define HALO  4
#define TCOLS 16           // 8 + 2*4  == DPP row width (16 lanes)
#define TROWS 40           // 32 + 2*4
#define NT    640          // 10 waves; wave w owns tile rows [4w, 4w+4)
#define NW    10
#define NB    256          // 32x8 blocks, one per CU

typedef float v4f __attribute__((ext_vector_type(4)));

#define AG __HIP_MEMORY_SCOPE_AGENT
__device__ __forceinline__ float agload (const float* p){ return __hip_atomic_load (p, __ATOMIC_RELAXED, AG); }
__device__ __forceinline__ int   agloadi(const int* p)  { return __hip_atomic_load (p, __ATOMIC_RELAXED, AG); }
__device__ __forceinline__ void  agstoref(float* p,float v){      __hip_atomic_store(p, v, __ATOMIC_RELAXED, AG); }
__device__ __forceinline__ void  agstorei(int* p,int v) {         __hip_atomic_store(p, v, __ATOMIC_RELAXED, AG); }

// Device-scope (sc1) 16B accesses, coherent at Infinity Cache. Stamp rides in
// .w -> each halo cell self-validates. Load+waitcnt in ONE asm block (R5 fault:
// split issue/wait lets regalloc retire the dest quad before the write lands).
__device__ __forceinline__ v4f ld16_dev(const v4f* p) {
    v4f r;
    asm volatile("global_load_dwordx4 %0, %1, off sc1\n\ts_waitcnt vmcnt(0)"
                 : "=v"(r) : "v"(p) : "memory");
    return r;
}
__device__ __forceinline__ void st16_dev(v4f* p, v4f v) {
    asm volatile("global_store_dwordx4 %0, %1, off sc1" :: "v"(p), "v"(v) : "memory");
}

// DPP register exchange within a 16-lane row (== one tile row).
// row_shr:1 (0x111): lane i reads lane i-1  -> LEFT  neighbor's register.
// row_shl:1 (0x101): lane i reads lane i+1  -> RIGHT neighbor's register.
// bound_ctrl=false: out-of-row source -> keep old (=self), which IS the old
// kernel's tile-edge self-clamp (offL/offR = 0). No LDS traffic.
__device__ __forceinline__ float dpp_lft(float v) {
    return __int_as_float(__builtin_amdgcn_update_dpp(
        __float_as_int(v), __float_as_int(v), 0x111, 0xF, 0xF, false));
}
__device__ __forceinline__ float dpp_rgt(float v) {
    return __int_as_float(__builtin_amdgcn_update_dpp(
        __float_as_int(v), __float_as_int(v), 0x101, 0xF, 0xF, false));
}

__global__ void __launch_bounds__(NT)
mm_solver(const float* __restrict__ signal,
          const float* __restrict__ B_ext,
          const float* __restrict__ Msat,
          const float* __restrict__ src_mask,
          const float* __restrict__ probe_mask,
          float* __restrict__ out,
          float* __restrict__ ws)
{
    const int b  = (int)blockIdx.x;
    const int bx = b & 31, by = b >> 5;
    const int t  = (int)threadIdx.x;
    const int tr = t >> 4, tc = t & 15;      // 16-wide rows: row == DPP row
    const int wv = t >> 6;                   // wave id 0..9

    const int grow = by * OWNH - HALO + tr;
    const int gcol = bx * OWNW - HALO + tc;
    const bool inG = (grow >= 0 && grow < 256 && gcol >= 0 && gcol < 256);
    const bool own = (tr >= HALO && tr < HALO + OWNH && tc >= HALO && tc < HALO + OWNW);

    // ws: pub v4f[2][65536] (2MB) | priv float[NB][TST] (1MB) | doneA int[NB]
    v4f*   pub   = (v4f*)ws;
    float* priv  = ws + 2 * 65536 * 4;
    int*   doneA = (int*)(priv + NB * TST);
    const int pubStride = 65536;

    __shared__ v4f  EB[2][TROWS * TCOLS];    // 20 KB, u/d stencil only (l/r = DPP)
    __shared__ float sigS[TST];
    // Paired phase counters: reader wave w spins on ONE aligned b64
    // {ctr[w-1], ctr[w+1]} at pair index w+1; writer w stores its counter into
    // the two pair cells where it appears (cpr[2w+1] and cpr[2w+4]).
    // Sentinels: cpr[2] (wave 0's left) and cpr[2*NW+1] (wave NW-1's right).
    __shared__ alignas(8) int cpr[2 * (NW + 2)];
    __shared__ int   hasP;
    __shared__ int   pfl[NB];
    __shared__ float redS[16];
    __shared__ float pmsS;

    // Wave-pipelined sync (no in-loop block barriers). With 16-wide rows and
    // 64-lane waves, u/d neighbors (rank +-16) are in waves w-1/w/w+1; l/r
    // neighbors are lane +-1 IN-WAVE (DPP, lockstep, no sync needed at all).
    // Global phase g = 4*i + p, p=0:m-write, 1:e1, 2:e2, 3:e3; phase p writes
    // EB[p&1]. Wave publishes counter=g after lgkmcnt(0). Rules unchanged from
    // the 24x24 kernel (monotone nearest-wave deps -> deadlock-free):
    //  * eval of phase-g data: spin neighbors >= g.
    //  * write of phase g+1 (overwrites g-1): covered by the spin >= g.
    volatile long long* cpp = (volatile long long*)&cpr[2 * (wv + 1)];
    volatile int*       cwl = (volatile int*)&cpr[2 * wv + 1];
    volatile int*       cwr = (volatile int*)&cpr[2 * wv + 4];
    const bool lane0 = ((t & 63) == 0);

#define PUB_CTR(G) do { \
    asm volatile("s_waitcnt lgkmcnt(0)" ::: "memory"); \
    if (lane0) { *cwl = (G); *cwr = (G); } \
    asm volatile("" ::: "memory"); \
} while (0)
#define SPIN_NBR(G) do { \
    for (;;) { long long v_ = *cpp; \
        if ((int)v_ >= (G) && (int)(v_ >> 32) >= (G)) break; } \
    asm volatile("" ::: "memory"); \
} while (0)

    // constants (identical fp expressions to the bitwise-validated kernels)
    const float invd   = (float)(1.0 / (double)((float)(50e-9 * 50e-9)));
    const float h      = (float)(1.7595e11 * 5e-12);
    const float hh     = (float)(0.5 * (1.7595e11 * 5e-12));
    const float h6     = (float)((1.7595e11 * 5e-12) / 6.0);
    const float alpha  = 0.01f;
    const float inv1a2 = (float)(1.0 / (1.0 + 0.01 * 0.01));

    const int growc = grow < 0 ? 0 : (grow > 255 ? 255 : grow);
    const int gcolc = gcol < 0 ? 0 : (gcol > 255 ? 255 : gcol);
    const int idxg  = growc * 256 + gcolc;
    const float bxv = B_ext[idxg], byv = B_ext[65536 + idxg], bzv = B_ext[131072 + idxg];
    const float ms  = Msat[idxg];
    const float sxv = src_mask[idxg], syv = src_mask[65536 + idxg], szv = src_mask[131072 + idxg];
    const float pm  = probe_mask[idxg];
    const float ce   = 7.3e-12f / ms;
    const float cdem = -(float)(4.0e-7 * 3.14159265358979323846) * ms;

    // u/d offsets: physical Neumann clamp (exact) + tile-edge clamp (cone
    // invariant: stage-s garbage confined to rings < s; own cells at rings
    // >= 4 never consume it within the 4 stages). l/r: DPP self-clamp at row
    // ends (tile edge) + canL/canR cndmask for the physical grid edge.
    const int idx  = t;
    const int offU = ((tr < TROWS - 1) && (grow < 255)) ?  TCOLS : 0;
    const int offD = ((tr > 0)         && (grow > 0))   ? -TCOLS : 0;
    const bool canL = (gcol > 0);
    const bool canR = (gcol < 255);

    const int slotOff = idxg;                 // poll slot (own: == publish slot)

    // relax() is bitwise identity (B_ext || z, m == z -> zero torque at every
    // stage). m0 = z-hat, m0x = 0 exactly. m_0 is KNOWN, so step 0 needs no
    // halo poll at all; owners pre-stamp parity-1 with -1 so no garbage stamp
    // can ever validate a poll before the first real publish (stamp 1).
    float mx = 0.0f, my = 0.0f, mz = 1.0f;

    if (own) {
        st16_dev(pub + slotOff,             (v4f){0.0f, 0.0f, 1.0f, __int_as_float(0)});
        st16_dev(pub + pubStride + slotOff, (v4f){0.0f, 0.0f, 1.0f, __int_as_float(-1)});
    }
    for (int k = t; k < TST; k += NT) sigS[k] = signal[k];
    if (t < 2 * (NW + 2))
        cpr[t] = ((t == 2) || (t == 2 * NW + 1)) ? 0x7fffffff : -1;   // sentinels
    if (t == 30) hasP = 0;
    __syncthreads();
    const bool pcell = own && (pm != 0.0f);
    if (pcell) atomicOr(&hasP, 1);
    const bool waveP = (__ballot(pcell) != 0ull);   // wave-uniform
    __syncthreads();
    const int hasPr = hasP;
    if (hasPr) for (int k = t; k < TST; k += NT) agstoref(&priv[b * TST + k], 0.0f);
    __syncthreads();   // TRUE barrier: drain zero-stores before step-0 probe atomics

    const bool haloT = inG && !own;
    float ex, ey, ez, ax, ay, az, kx, ky, kz, btx, bty, btz;

#define STAGE(SB) do { \
    const v4f u = EB[SB][idx + offU]; \
    const v4f d = EB[SB][idx + offD]; \
    float rX = dpp_rgt(ex), rY = dpp_rgt(ey), rZ = dpp_rgt(ez); \
    float lX = dpp_lft(ex), lY = dpp_lft(ey), lZ = dpp_lft(ez); \
    rX = canR ? rX : ex;  rY = canR ? rY : ey;  rZ = canR ? rZ : ez; \
    lX = canL ? lX : ex;  lY = canL ? lY : ey;  lZ = canL ? lZ : ez; \
    float lx = ((u.x + d.x - 2.0f * ex) + (rX + lX - 2.0f * ex)) * invd; \
    float ly = ((u.y + d.y - 2.0f * ey) + (rY + lY - 2.0f * ey)) * invd; \
    float lz = ((u.z + d.z - 2.0f * ez) + (rZ + lZ - 2.0f * ez)) * invd; \
    float Bx = btx + ce * lx; \
    float By = bty + ce * ly; \
    float Bz = btz + ce * lz + cdem * ez; \
    float cx = ey * Bz - ez * By; \
    float cy = ez * Bx - ex * Bz; \
    float cz = ex * By - ey * Bx; \
    float dx = ey * cz - ez * cy; \
    float dy = ez * cx - ex * cz; \
    float dz = ex * cy - ey * cx; \
    kx = -(cx + alpha * dx) * inv1a2; \
    ky = -(cy + alpha * dy) * inv1a2; \
    kz = -(cz + alpha * dz) * inv1a2; \
} while (0)

#define WRE(DB) do { EB[DB][idx] = (v4f){ex, ey, ez, 0.0f}; } while (0)

    for (int i = 0; i < TST; ++i) {
        const float s = sigS[i];
        const int  g0 = i << 2;

        // Halo refresh: poll my cell's stamped slot (parity i&1) until stamp>=i.
        // Skipped at i==0 (m_0 known analytically -> registers already hold it).
        // Skew<=1 at wave granularity: OUR wave's publish of m_{i+1} follows OUR
        // poll of m_i in program order; the owner needs our stamp i+1 before it
        // can write i+2 into this parity slot (cross-block chain strictly
        // decreases step index -> no premature overwrite, no deadlock).
        if (haloT && i) {
            const v4f* p = pub + (i & 1) * pubStride + slotOff;
            for (;;) {
                v4f hv = ld16_dev(p);
                if (__float_as_int(hv.w) >= i) { mx = hv.x; my = hv.y; mz = hv.z; break; }
            }
        }

        btx = bxv + s * sxv;  bty = byv + s * syv;  btz = bzv + s * szv;
        ex = mx; ey = my; ez = mz;
        WRE(0);                           // phase g0: expose m (u/d consumers)
        PUB_CTR(g0);                      //  (m-write overwrites e2 of step i-1:
                                          //   covered by last step's spin >= g0-1)
        SPIN_NBR(g0);
        STAGE(0);                         // k1
        ax = kx; ay = ky; az = kz;
        ex = mx + hh * kx; ey = my + hh * ky; ez = mz + hh * kz;
        WRE(1);                           // phase g0+1
        PUB_CTR(g0 + 1);

        SPIN_NBR(g0 + 1);
        STAGE(1);                         // k2
        ax += 2.0f * kx; ay += 2.0f * ky; az += 2.0f * kz;
        ex = mx + hh * kx; ey = my + hh * ky; ez = mz + hh * kz;
        WRE(0);                           // phase g0+2
        PUB_CTR(g0 + 2);

        SPIN_NBR(g0 + 2);
        STAGE(0);                         // k3
        ax += 2.0f * kx; ay += 2.0f * ky; az += 2.0f * kz;
        ex = mx + h * kx; ey = my + h * ky; ez = mz + h * kz;
        WRE(1);                           // phase g0+3
        PUB_CTR(g0 + 3);

        SPIN_NBR(g0 + 3);
        STAGE(1);                         // k4
        ax += kx; ay += ky; az += kz;
        mx += h6 * ax; my += h6 * ay; mz += h6 * az;

        // publish m_{i+1}, stamp i+1, parity (i+1)&1 (fire-and-forget, global)
        if (own) st16_dev(pub + ((i + 1) & 1) * pubStride + slotOff,
                          (v4f){mx, my, mz, __int_as_float(i + 1)});

        // probe: (mx - m0x) = mx exactly; per-wave reduce -> one atomic
        if (waveP) {
            float c = pcell ? mx * ms * pm : 0.0f;
            #pragma unroll
            for (int off = 32; off > 0; off >>= 1) c += __shfl_down(c, off, 64);
            if (lane0) atomicAdd(&priv[b * TST + i], c);
        }
    }

    // ---- finalize ----
    __syncthreads();   // TRUE barrier: drains vmcnt -> publishes/atomics done
    if (t == 0) agstorei(&doneA[b], 0x5D0000 | hasPr);

    if (b == 0) {
        if (t < NB) {
            int v;
            for (;;) { v = agloadi(&doneA[t]); if ((v & ~1) == 0x5D0000) break;
                       __builtin_amdgcn_s_sleep(8); }
            pfl[t] = v & 1;
        }
        __syncthreads();
        float ps = 0.0f;
        for (int k = t; k < 65536; k += NT) ps += probe_mask[k];
        #pragma unroll
        for (int off = 32; off > 0; off >>= 1) ps += __shfl_down(ps, off, 64);
        if (lane0) redS[wv] = ps;
        __syncthreads();
        if (t == 0) { float q = 0.0f; for (int w = 0; w < NW; ++w) q += redS[w]; pmsS = q; }
        __syncthreads();
        const float pms = pmsS;
        for (int o = t; o < TST; o += NT) {
            float sm = 0.0f;
            for (int j = 0; j < NB; ++j) if (pfl[j]) sm += agload(&priv[j * TST + o]);
            out[o] = sm / pms;
        }
    }
}

extern "C" void kernel_launch(void* const* d_in, const int* in_sizes, int n_in,
                              void* d_out, int out_size, void* d_ws, size_t ws_size,
                              hipStream_t stream)
{
    const float* signal = (const float*)d_in[0];
    const float* B_ext  = (const float*)d_in[1];
    const float* Msat   = (const float*)d_in[2];
    const float* src    = (const float*)d_in[3];
    const float* probe  = (const float*)d_in[4];
    float* out = (float*)d_out;
    float* ws  = (float*)d_ws;

    void* args[] = { &signal, &B_ext, &Msat, &src, &probe, &out, &ws };
    (void)in_sizes; (void)n_in; (void)out_size; (void)ws_size;

    // 256 blocks (32x8 own tiles) x 640 threads. Tile rows == 16-lane DPP rows:
    // l/r stencil neighbors come from lane+-1 registers (no LDS), u/d from LDS.
    // NO in-loop block barriers: waves pipeline through the 4 RK4 stages gated
    // only by nearest-wave paired LDS phase counters; cross-block sync is
    // stamped point-to-point through IF$.
    hipLaunchCooperativeKernel(reinterpret_cast<void*>(mm_solver),
                               dim3(NB), dim3(NT), args, 0, stream);
}

// Round 5
// 2745.528 us; speedup vs baseline: 1.1170x; 1.1170x over previous
//
#include <hip/hip_runtime.h>

#define TST   1024
#define OWN   16           // own tile: 16x16
#define HALO  8            // 8 rings -> 8 stages -> 2 RK4 steps per exchange
#define TDIM  32           // 32x32 tile = own 16x16 + 8-halo
#define NT    1024         // 16 waves; wave w owns tile rows [2w, 2w+2)
#define NW    16
#define NB    256          // 16x16 blocks, one per CU

typedef float v4f __attribute__((ext_vector_type(4)));

#define AG __HIP_MEMORY_SCOPE_AGENT
__device__ __forceinline__ float agload (const float* p){ return __hip_atomic_load (p, __ATOMIC_RELAXED, AG); }
__device__ __forceinline__ int   agloadi(const int* p)  { return __hip_atomic_load (p, __ATOMIC_RELAXED, AG); }
__device__ __forceinline__ void  agstoref(float* p,float v){      __hip_atomic_store(p, v, __ATOMIC_RELAXED, AG); }
__device__ __forceinline__ void  agstorei(int* p,int v) {         __hip_atomic_store(p, v, __ATOMIC_RELAXED, AG); }

// Device-scope (sc1) 16B accesses, coherent at Infinity Cache. Stamp rides in
// .w -> each halo cell self-validates. Load+waitcnt in ONE asm block (R5 fault:
// split issue/wait lets regalloc retire the dest quad before the write lands).
__device__ __forceinline__ v4f ld16_dev(const v4f* p) {
    v4f r;
    asm volatile("global_load_dwordx4 %0, %1, off sc1\n\ts_waitcnt vmcnt(0)"
                 : "=v"(r) : "v"(p) : "memory");
    return r;
}
__device__ __forceinline__ void st16_dev(v4f* p, v4f v) {
    asm volatile("global_store_dwordx4 %0, %1, off sc1" :: "v"(p), "v"(v) : "memory");
}

__global__ void __launch_bounds__(NT)
mm_solver(const float* __restrict__ signal,
          const float* __restrict__ B_ext,
          const float* __restrict__ Msat,
          const float* __restrict__ src_mask,
          const float* __restrict__ probe_mask,
          float* __restrict__ out,
          float* __restrict__ ws)
{
    const int b  = (int)blockIdx.x;
    const int bx = b & 15, by = b >> 4;
    const int t  = (int)threadIdx.x;
    const int tr = t >> 5, tc = t & 31;      // 32-wide rows, rank == t
    const int wv = t >> 6;                   // wave id 0..15 (2 tile rows each)

    const int grow = by * OWN - HALO + tr;
    const int gcol = bx * OWN - HALO + tc;
    const bool inG = (grow >= 0 && grow < 256 && gcol >= 0 && gcol < 256);
    const bool own = (tr >= HALO && tr < HALO + OWN && tc >= HALO && tc < HALO + OWN);

    // ws: pub v4f[2][65536] (2MB) | priv float[NB][TST] (1MB) | doneA int[NB]
    v4f*   pub   = (v4f*)ws;
    float* priv  = ws + 2 * 65536 * 4;
    int*   doneA = (int*)(priv + NB * TST);
    const int pubStride = 65536;

    __shared__ v4f  EB[2][TDIM * TDIM];      // 32 KB exposure buffers
    __shared__ float sigS[TST];
    __shared__ int  wctr[NW + 2];            // per-wave phase counters + sentinels
    __shared__ int   hasP;
    __shared__ int   pfl[NB];
    __shared__ float redS[16];
    __shared__ float pmsS;

    // Wave-pipelined sync (no in-loop block barriers). 32-wide rows, 64-lane
    // waves: u/d neighbors (rank +-32) are in waves w-1/w/w+1; l/r neighbors
    // are rank +-1 (same wave, LDS). Global phase g = 8*I + p for 2-step group
    // I, p=0..7 (two RK4 steps: m,e1,e2,e3 twice); phase p writes EB[p&1].
    // Wave publishes counter=g after lgkmcnt(0). Invariants (same algebra as
    // the validated 4-phase baseline, monotone nearest-wave deps -> no
    // deadlock):
    //  * eval of phase-g data: spin neighbors >= g.
    //  * write of phase g+2's slot (overwrites g): readers of g published g+1
    //    first (lgkmcnt(0) covers their reads) -> our SPIN >= g+1 covers it.
    // Cross-block overwrite-after-read: A overwrites a pub slot (stamp I+2)
    // only after its halo polled I+1 from B <= B finished group I <= (wave
    // chain, max distance 7 <= 7 phases) B's halo waves completed their
    // group-I poll -- the protected read. Corners included (corner halo lanes
    // are in waves 0-3/12-15 which the chain reaches). Counter scheme is the
    // BASELINE's proven dual-b32 spin, scaled to NW=16.
    volatile int* cl  = (volatile int*)&wctr[wv];        // left nbr (sentinel @0)
    volatile int* cr  = (volatile int*)&wctr[wv + 2];    // right nbr (sentinel @NW+1)
    volatile int* cme = (volatile int*)&wctr[wv + 1];
    const bool lane0 = ((t & 63) == 0);

#define PUB_CTR(G) do { \
    asm volatile("s_waitcnt lgkmcnt(0)" ::: "memory"); \
    if (lane0) *cme = (G); \
    asm volatile("" ::: "memory"); \
} while (0)
#define SPIN_NBR(G) do { \
    while (*cl < (G)) {} \
    while (*cr < (G)) {} \
    asm volatile("" ::: "memory"); \
} while (0)

    // constants (identical fp expressions to the bitwise-validated kernels)
    const float invd   = (float)(1.0 / (double)((float)(50e-9 * 50e-9)));
    const float h      = (float)(1.7595e11 * 5e-12);
    const float hh     = (float)(0.5 * (1.7595e11 * 5e-12));
    const float h6     = (float)((1.7595e11 * 5e-12) / 6.0);
    const float alpha  = 0.01f;
    const float inv1a2 = (float)(1.0 / (1.0 + 0.01 * 0.01));

    const int growc = grow < 0 ? 0 : (grow > 255 ? 255 : grow);
    const int gcolc = gcol < 0 ? 0 : (gcol > 255 ? 255 : gcol);
    const int idxg  = growc * 256 + gcolc;
    const float bxv = B_ext[idxg], byv = B_ext[65536 + idxg], bzv = B_ext[131072 + idxg];
    const float ms  = Msat[idxg];
    const float sxv = src_mask[idxg], syv = src_mask[65536 + idxg], szv = src_mask[131072 + idxg];
    const float pm  = probe_mask[idxg];
    const float ce   = 7.3e-12f / ms;
    const float cdem = -(float)(4.0e-7 * 3.14159265358979323846) * ms;

    // Neighbor offsets: physical Neumann clamp (exact) + tile-edge clamp.
    // Cone invariant for HALO=8: ring-k values valid through stage 8-k
    // (edge garbage advances one ring per stage); own cells (ring>=8) stay
    // exact through all 8 stages of the 2-step group. Row-uniform offsets.
    const int idx  = t;
    const int offU = ((tr < TDIM - 1) && (grow < 255)) ?  TDIM : 0;
    const int offD = ((tr > 0)        && (grow > 0))   ? -TDIM : 0;
    const int offR = ((tc < TDIM - 1) && (gcol < 255)) ?  1 : 0;
    const int offL = ((tc > 0)        && (gcol > 0))   ? -1 : 0;

    const int slotOff = idxg;                 // poll slot (own: == publish slot)

    // relax() is bitwise identity (B_ext || z, m == z -> zero torque at every
    // stage). m0 = z-hat, m0x = 0 exactly. m_0 is KNOWN, so group 0 needs no
    // halo poll; owners pre-stamp parity-1 with -1 so no garbage stamp can
    // validate a poll before the first real publish (stamp 1).
    float mx = 0.0f, my = 0.0f, mz = 1.0f;

    if (own) {
        st16_dev(pub + slotOff,             (v4f){0.0f, 0.0f, 1.0f, __int_as_float(0)});
        st16_dev(pub + pubStride + slotOff, (v4f){0.0f, 0.0f, 1.0f, __int_as_float(-1)});
    }
    for (int k = t; k < TST; k += NT) sigS[k] = signal[k];
    if (t < NW + 2)
        wctr[t] = ((t == 0) || (t == NW + 1)) ? 0x7fffffff : -1;   // sentinels
    if (t == 40) hasP = 0;
    __syncthreads();
    const bool pcell = own && (pm != 0.0f);
    if (pcell) atomicOr(&hasP, 1);
    const bool waveP = (__ballot(pcell) != 0ull);   // wave-uniform
    __syncthreads();
    const int hasPr = hasP;
    if (hasPr) for (int k = t; k < TST; k += NT) agstoref(&priv[b * TST + k], 0.0f);
    __syncthreads();   // TRUE barrier: drain zero-stores before step-0 probe atomics

    const bool haloT = inG && !own;
    float ex, ey, ez, ax, ay, az, kx, ky, kz, btx, bty, btz;

#define STAGE(SB) do { \
    const v4f u = EB[SB][idx + offU]; \
    const v4f d = EB[SB][idx + offD]; \
    const v4f r = EB[SB][idx + offR]; \
    const v4f l = EB[SB][idx + offL]; \
    float lx = ((u.x + d.x - 2.0f * ex) + (r.x + l.x - 2.0f * ex)) * invd; \
    float ly = ((u.y + d.y - 2.0f * ey) + (r.y + l.y - 2.0f * ey)) * invd; \
    float lz = ((u.z + d.z - 2.0f * ez) + (r.z + l.z - 2.0f * ez)) * invd; \
    float Bx = btx + ce * lx; \
    float By = bty + ce * ly; \
    float Bz = btz + ce * lz + cdem * ez; \
    float cx = ey * Bz - ez * By; \
    float cy = ez * Bx - ex * Bz; \
    float cz = ex * By - ey * Bx; \
    float dx = ey * cz - ez * cy; \
    float dy = ez * cx - ex * cz; \
    float dz = ex * cy - ey * cx; \
    kx = -(cx + alpha * dx) * inv1a2; \
    ky = -(cy + alpha * dy) * inv1a2; \
    kz = -(cz + alpha * dz) * inv1a2; \
} while (0)

#define WRE(DB) do { EB[DB][idx] = (v4f){ex, ey, ez, 0.0f}; } while (0)

// One full RK4 step: 4 phases GB..GB+3, signal S, then m += update.
#define RK4_STEP(GB, S) do { \
    btx = bxv + (S) * sxv;  bty = byv + (S) * syv;  btz = bzv + (S) * szv; \
    ex = mx; ey = my; ez = mz; \
    WRE(0);  PUB_CTR(GB); \
    SPIN_NBR(GB);      STAGE(0);       /* k1 */ \
    ax = kx; ay = ky; az = kz; \
    ex = mx + hh * kx; ey = my + hh * ky; ez = mz + hh * kz; \
    WRE(1);  PUB_CTR((GB) + 1); \
    SPIN_NBR((GB) + 1); STAGE(1);      /* k2 */ \
    ax += 2.0f * kx; ay += 2.0f * ky; az += 2.0f * kz; \
    ex = mx + hh * kx; ey = my + hh * ky; ez = mz + hh * kz; \
    WRE(0);  PUB_CTR((GB) + 2); \
    SPIN_NBR((GB) + 2); STAGE(0);      /* k3 */ \
    ax += 2.0f * kx; ay += 2.0f * ky; az += 2.0f * kz; \
    ex = mx + h * kx; ey = my + h * ky; ez = mz + h * kz; \
    WRE(1);  PUB_CTR((GB) + 3); \
    SPIN_NBR((GB) + 3); STAGE(1);      /* k4 */ \
    ax += kx; ay += ky; az += kz; \
    mx += h6 * ax; my += h6 * ay; mz += h6 * az; \
} while (0)

#define PROBE(I_) do { \
    if (waveP) { \
        float c = pcell ? mx * ms * pm : 0.0f; \
        _Pragma("unroll") \
        for (int off = 32; off > 0; off >>= 1) c += __shfl_down(c, off, 64); \
        if (lane0) atomicAdd(&priv[b * TST + (I_)], c); \
    } \
} while (0)

    for (int i = 0; i < TST; i += 2) {
        const int I = i >> 1;                 // 2-step group index

        // Halo refresh ONCE per group: poll my cell's stamped slot (parity
        // I&1) until stamp>=I. Skipped at I==0 (m_0 known analytically).
        // First poll tight (common case: neighbor ahead, hit immediately);
        // on miss, s_sleep(1) backoff (~64cy) to avoid hammering the IF$
        // fabric (R2 showed a 14x outlier dispatch consistent with spin
        // contention). Cross-block chain strictly decreases group index ->
        // no premature overwrite, no deadlock.
        if (haloT && I) {
            const v4f* p = pub + (I & 1) * pubStride + slotOff;
            for (;;) {
                v4f hv = ld16_dev(p);
                if (__float_as_int(hv.w) >= I) { mx = hv.x; my = hv.y; mz = hv.z; break; }
                __builtin_amdgcn_s_sleep(1);
            }
        }

        const int g0 = I << 3;                // 8 phases per group

        RK4_STEP(g0,     sigS[i]);            // step A -> m_{i+1}
        PROBE(i);
        RK4_STEP(g0 + 4, sigS[i + 1]);        // step B -> m_{i+2}
        PROBE(i + 1);

        // publish m_{i+2}, stamp I+1, parity (I+1)&1 (fire-and-forget, global)
        if (own) st16_dev(pub + ((I + 1) & 1) * pubStride + slotOff,
                          (v4f){mx, my, mz, __int_as_float(I + 1)});
    }

    // ---- finalize ----
    __syncthreads();   // TRUE barrier: drains vmcnt -> publishes/atomics done
    if (t == 0) agstorei(&doneA[b], 0x5D0000 | hasPr);

    if (b == 0) {
        if (t < NB) {
            int v;
            for (;;) { v = agloadi(&doneA[t]); if ((v & ~1) == 0x5D0000) break;
                       __builtin_amdgcn_s_sleep(8); }
            pfl[t] = v & 1;
        }
        __syncthreads();
        float ps = 0.0f;
        for (int k = t; k < 65536; k += NT) ps += probe_mask[k];
        #pragma unroll
        for (int off = 32; off > 0; off >>= 1) ps += __shfl_down(ps, off, 64);
        if (lane0) redS[wv] = ps;
        __syncthreads();
        if (t == 0) { float q = 0.0f; for (int w = 0; w < NW; ++w) q += redS[w]; pmsS = q; }
        __syncthreads();
        const float pms = pmsS;
        for (int o = t; o < TST; o += NT) {
            float sm = 0.0f;
            for (int j = 0; j < NB; ++j) if (pfl[j]) sm += agload(&priv[j * TST + o]);
            out[o] = sm / pms;
        }
    }
}

extern "C" void kernel_launch(void* const* d_in, const int* in_sizes, int n_in,
                              void* d_out, int out_size, void* d_ws, size_t ws_size,
                              hipStream_t stream)
{
    const float* signal = (const float*)d_in[0];
    const float* B_ext  = (const float*)d_in[1];
    const float* Msat   = (const float*)d_in[2];
    const float* src    = (const float*)d_in[3];
    const float* probe  = (const float*)d_in[4];
    float* out = (float*)d_out;
    float* ws  = (float*)d_ws;

    void* args[] = { &signal, &B_ext, &Msat, &src, &probe, &out, &ws };
    (void)in_sizes; (void)n_in; (void)out_size; (void)ws_size;

    // 256 blocks (16x16 own tiles, 8-deep halo) x 1024 threads. Cross-block
    // exchange every 2 RK4 steps (8-stage cone): halves the per-step global
    // IF$ round-trips, the dominant serial-latency term. NO in-loop block
    // barriers: 16 waves pipeline through 8 phases/group gated only by
    // nearest-wave LDS phase counters (baseline's proven dual-b32 scheme).
    hipLaunchCooperativeKernel(reinterpret_cast<void*>(mm_solver),
                               dim3(NB), dim3(NT), args, 0, stream);
}